// Round 1
// 218.397 us; speedup vs baseline: 1.1001x; 1.1001x over previous
//
#include <hip/hip_runtime.h>

// Problem: B=32, C=3, H=512, W=512 -> NIMG = 96 flat images
// ONE kernel: per block (img, 16x16-pooled tile):
//   phase 0: Haar DWT of x -> cA 70x70 tile in LDS (zero-pad OOB); interior
//            64x64 cH/cV written straight to d_out high region.
//   phase a/b (x4 ic-chunks): conv1(1->16)+relu+pool2 -> LDS, conv2(16->8) accum.
//   epilogue: relu+pool2, conv3(8->4,1x1) -> d_out low region.
// R1 change: conv1/conv2 inner loops use v_pk_fma_f32 (packed fp32, 2 FMA/instr
//   — MI355X's 157 TF fp32 rate) packed over OUTPUT-CHANNEL pairs.
//   Activation broadcast is free via VOP3P op_sel on the LDS-loaded pair;
//   weights are wave-uniform SGPR pairs (SALU-built, 1 SGPR read/instr).
//   Math order/values bit-identical to scalar version.

typedef float v2f __attribute__((ext_vector_type(2)));

// acc(pair over oc) += w(pair over oc, SGPR) * broadcast(data.word0)
#define PK_FMA_W0(acc, w, d) \
    asm("v_pk_fma_f32 %0, %1, %2, %0 op_sel:[0,0,0] op_sel_hi:[1,0,1]" \
        : "+v"(acc) : "s"(w), "v"(d))
// acc += w * broadcast(data.word1)
#define PK_FMA_W1(acc, w, d) \
    asm("v_pk_fma_f32 %0, %1, %2, %0 op_sel:[0,1,0] op_sel_hi:[1,1,1]" \
        : "+v"(acc) : "s"(w), "v"(d))
// dst = w * broadcast(data.word0)   (accumulator init without v_mov zeroing)
#define PK_MUL_W0(dst, w, d) \
    asm("v_pk_mul_f32 %0, %1, %2 op_sel:[0,0] op_sel_hi:[1,0]" \
        : "=v"(dst) : "s"(w), "v"(d))
#define PK_MUL_W1(dst, w, d) \
    asm("v_pk_mul_f32 %0, %1, %2 op_sel:[0,1] op_sel_hi:[1,1]" \
        : "=v"(dst) : "s"(w), "v"(d))

__global__ __launch_bounds__(256, 4) void fused_all_kernel(
    const float* __restrict__ x,
    const float* __restrict__ w1, const float* __restrict__ b1,
    const float* __restrict__ w2, const float* __restrict__ b2,
    const float* __restrict__ w3, const float* __restrict__ b3,
    float* __restrict__ outLow, float* __restrict__ outHigh)
{
    __shared__ __align__(16) float ca[70 * 72];      // cA tile, rows stride 72
    __shared__ __align__(16) float h1s[4 * 34 * 36]; // conv1 output chunk

    int img = blockIdx.x >> 4;
    int t   = blockIdx.x & 15;
    int ty = t >> 2, tx = t & 3;               // 4x4 tiles over pooled-64 output
    int hy0 = ty * 32 - 1, hx0 = tx * 32 - 1;  // h1 tile origin (34x34 incl halo)
    int cy0 = ty * 64 - 3, cx0 = tx * 64 - 3;  // cA tile origin (70x70)

    const float* xi = x + img * 262144;        // 512*512 image
    float* hb = outHigh + img * 131072;

    // ---- Phase 0a: interior 64x64 cA (coalesced), cH/cV -> global ----
    #pragma unroll
    for (int k = 0; k < 4; ++k) {
        int i = threadIdx.x + k * 256;
        int row = i >> 4, cg = i & 15;
        int gy = ty * 64 + row;                // cA row (always in-bounds)
        int gx = tx * 64 + cg * 4;             // cA col, float4-aligned
        const float* r0 = xi + (2 * gy) * 512 + 2 * gx;
        const float* r1 = r0 + 512;
        float4 t0 = *(const float4*)(r0);
        float4 t1 = *(const float4*)(r0 + 4);
        float4 u0 = *(const float4*)(r1);
        float4 u1 = *(const float4*)(r1 + 4);
        float4 vA, vH, vV;
        vA.x = (t0.x + t0.y + u0.x + u0.y) * 0.5f;
        vH.x = (t0.x + t0.y - u0.x - u0.y) * 0.5f;
        vV.x = (t0.x - t0.y + u0.x - u0.y) * 0.5f;
        vA.y = (t0.z + t0.w + u0.z + u0.w) * 0.5f;
        vH.y = (t0.z + t0.w - u0.z - u0.w) * 0.5f;
        vV.y = (t0.z - t0.w + u0.z - u0.w) * 0.5f;
        vA.z = (t1.x + t1.y + u1.x + u1.y) * 0.5f;
        vH.z = (t1.x + t1.y - u1.x - u1.y) * 0.5f;
        vV.z = (t1.x - t1.y + u1.x - u1.y) * 0.5f;
        vA.w = (t1.z + t1.w + u1.z + u1.w) * 0.5f;
        vH.w = (t1.z + t1.w - u1.z - u1.w) * 0.5f;
        vV.w = (t1.z - t1.w + u1.z - u1.w) * 0.5f;
        int po = (gy << 8) + gx;
        *(float4*)(hb + po) = vH;
        *(float4*)(hb + 65536 + po) = vV;
        float* cp = ca + (row + 3) * 72 + cg * 4 + 3;   // odd offset: scalar stores
        cp[0] = vA.x; cp[1] = vA.y; cp[2] = vA.z; cp[3] = vA.w;
    }

    // ---- Phase 0b: 3-wide halo ring of cA (804 points), vA only ----
    for (int i = threadIdx.x; i < 804; i += 256) {
        int r, c;
        if (i < 210)      { r = i / 70;              c = i - r * 70; }
        else if (i < 420) { int j = i - 210; r = 67 + j / 70; c = j - (j / 70) * 70; }
        else              { int j = i - 420; r = 3 + j / 6; int k6 = j - (j / 6) * 6;
                            c = (k6 < 3) ? k6 : (64 + k6); }   // {0,1,2,67,68,69}
        int gy = cy0 + r, gx = cx0 + c;
        float v = 0.f;
        if ((unsigned)gy < 256u && (unsigned)gx < 256u) {
            const float* p0 = xi + (2 * gy) * 512 + 2 * gx;
            float2 a = *(const float2*)(p0);
            float2 b = *(const float2*)(p0 + 512);
            v = (a.x + a.y + b.x + b.y) * 0.5f;
        }
        ca[r * 72 + c] = v;
    }

    int ly = threadIdx.x >> 4, lx = threadIdx.x & 15;  // pos in 16x16 pooled tile

    // conv2 accumulators: packed over oc pairs -> acc2[ocpair][r][c] = {oc_even, oc_odd}
    v2f acc2[4][2][2];
    #pragma unroll
    for (int o2 = 0; o2 < 4; ++o2)
        #pragma unroll
        for (int r = 0; r < 2; ++r)
            #pragma unroll
            for (int c = 0; c < 2; ++c) acc2[o2][r][c] = (v2f){0.f, 0.f};

    __syncthreads();

    #pragma unroll 1
    for (int cc = 0; cc < 4; ++cc) {
        // conv1 weight pairs over oc for this 4-oc chunk (uniform -> SGPR pairs)
        v2f wp1[2][9];
        #pragma unroll
        for (int o2 = 0; o2 < 2; ++o2)
            #pragma unroll
            for (int k = 0; k < 9; ++k)
                wp1[o2][k] = (v2f){ w1[(cc * 4 + o2 * 2    ) * 9 + k],
                                    w1[(cc * 4 + o2 * 2 + 1) * 9 + k] };
        if (cc) __syncthreads();   // prev chunk's conv2 reads before overwrite

        // Phase a: h1 chunk = pool2(relu(conv1)), 4 oc, 34x34 (incl conv2 halo)
        #pragma unroll 1
        for (int k5 = 0; k5 < 5; ++k5) {
            int i = threadIdx.x + k5 * 256;
            if (i < 1156) {
                int hy = i / 34, hx = i - hy * 34;
                const float* pb = ca + (2 * hy) * 72 + 2 * hx;
                v2f pr[4][2];
                #pragma unroll
                for (int r = 0; r < 4; ++r) {
                    pr[r][0] = *(const v2f*)(pb + r * 72);
                    pr[r][1] = *(const v2f*)(pb + r * 72 + 2);
                }
                bool oob = ((unsigned)(hy0 + hy) >= 128u) | ((unsigned)(hx0 + hx) >= 128u);
                v2f am[2][4];   // [ocpair][pos: p00 p01 p10 p11]
                #pragma unroll
                for (int ky = 0; ky < 3; ++ky)
                #pragma unroll
                for (int kx = 0; kx < 3; ++kx) {
                    #pragma unroll
                    for (int o2 = 0; o2 < 2; ++o2)
                    #pragma unroll
                    for (int dy = 0; dy < 2; ++dy)
                    #pragma unroll
                    for (int dx = 0; dx < 2; ++dx) {
                        v2f d = pr[ky + dy][(kx + dx) >> 1];
                        if (ky == 0 && kx == 0) {
                            if (((kx + dx) & 1) == 0) PK_MUL_W0(am[o2][dy * 2 + dx], wp1[o2][0], d);
                            else                      PK_MUL_W1(am[o2][dy * 2 + dx], wp1[o2][0], d);
                        } else {
                            if (((kx + dx) & 1) == 0) PK_FMA_W0(am[o2][dy * 2 + dx], wp1[o2][ky * 3 + kx], d);
                            else                      PK_FMA_W1(am[o2][dy * 2 + dx], wp1[o2][ky * 3 + kx], d);
                        }
                    }
                }
                #pragma unroll
                for (int o2 = 0; o2 < 2; ++o2) {
                    float mx = fmaxf(fmaxf(am[o2][0].x, am[o2][1].x),
                                     fmaxf(am[o2][2].x, am[o2][3].x));
                    float my = fmaxf(fmaxf(am[o2][0].y, am[o2][1].y),
                                     fmaxf(am[o2][2].y, am[o2][3].y));
                    mx = fmaxf(mx + b1[cc * 4 + o2 * 2    ], 0.f);
                    my = fmaxf(my + b1[cc * 4 + o2 * 2 + 1], 0.f);
                    h1s[((o2 * 2    ) * 34 + hy) * 36 + hx] = oob ? 0.f : mx;
                    h1s[((o2 * 2 + 1) * 34 + hy) * 36 + hx] = oob ? 0.f : my;
                }
            }
        }
        __syncthreads();

        // Phase b: conv2 accumulate over these 4 input channels
        #pragma unroll
        for (int icl = 0; icl < 4; ++icl) {
            const float* base = h1s + (icl * 34 + ly * 2) * 36 + lx * 2;
            v2f wr[4][2];
            #pragma unroll
            for (int r = 0; r < 4; ++r) {
                wr[r][0] = *(const v2f*)(base + r * 36);
                wr[r][1] = *(const v2f*)(base + r * 36 + 2);
            }
            int ic = cc * 4 + icl;
            #pragma unroll
            for (int ky = 0; ky < 3; ++ky)
            #pragma unroll
            for (int kx = 0; kx < 3; ++kx)
            #pragma unroll
            for (int o2 = 0; o2 < 4; ++o2) {
                v2f wv = (v2f){ w2[((o2 * 2    ) * 16 + ic) * 9 + ky * 3 + kx],
                                w2[((o2 * 2 + 1) * 16 + ic) * 9 + ky * 3 + kx] };
                #pragma unroll
                for (int r = 0; r < 2; ++r)
                #pragma unroll
                for (int c = 0; c < 2; ++c) {
                    v2f d = wr[r + ky][(c + kx) >> 1];
                    if (((c + kx) & 1) == 0) PK_FMA_W0(acc2[o2][r][c], wv, d);
                    else                     PK_FMA_W1(acc2[o2][r][c], wv, d);
                }
            }
        }
    }

    // Epilogue: bias+relu+pool2 of conv2, then conv3 (1x1, 8->4) -> low
    float h2v[8];
    #pragma unroll
    for (int o2 = 0; o2 < 4; ++o2) {
        float mx = fmaxf(fmaxf(acc2[o2][0][0].x, acc2[o2][0][1].x),
                         fmaxf(acc2[o2][1][0].x, acc2[o2][1][1].x));
        float my = fmaxf(fmaxf(acc2[o2][0][0].y, acc2[o2][0][1].y),
                         fmaxf(acc2[o2][1][0].y, acc2[o2][1][1].y));
        h2v[o2 * 2    ] = fmaxf(mx + b2[o2 * 2    ], 0.f);
        h2v[o2 * 2 + 1] = fmaxf(my + b2[o2 * 2 + 1], 0.f);
    }
    float* dst = outLow + img * 16384;
    int pos = (ty * 16 + ly) * 64 + tx * 16 + lx;
    #pragma unroll
    for (int oc3 = 0; oc3 < 4; ++oc3) {
        float s = b3[oc3];
        #pragma unroll
        for (int ic = 0; ic < 8; ++ic) s += w3[oc3 * 8 + ic] * h2v[ic];
        dst[oc3 * 4096 + pos] = s;
    }
}

extern "C" void kernel_launch(void* const* d_in, const int* in_sizes, int n_in,
                              void* d_out, int out_size, void* d_ws, size_t ws_size,
                              hipStream_t stream) {
    const float* x  = (const float*)d_in[0];
    const float* w1 = (const float*)d_in[1];
    const float* b1 = (const float*)d_in[2];
    const float* w2 = (const float*)d_in[3];
    const float* b2 = (const float*)d_in[4];
    const float* w3 = (const float*)d_in[5];
    const float* b3 = (const float*)d_in[6];
    float* out     = (float*)d_out;
    float* outLow  = out;                 // 1,572,864 floats
    float* outHigh = out + 1572864;       // 12,582,912 floats

    fused_all_kernel<<<1536, 256, 0, stream>>>(x, w1, b1, w2, b2, w3, b3,
                                               outLow, outHigh);
}

// Round 2
// 209.723 us; speedup vs baseline: 1.1456x; 1.0414x over previous
//
#include <hip/hip_runtime.h>

// Problem: B=32, C=3, H=512, W=512 -> NIMG = 96 flat images
// ONE kernel: per block (img, 8x16-pooled half-tile):
//   phase 0: Haar DWT of x -> cA 38x70 tile in LDS (zero-pad OOB); interior
//            32x64 cH/cV written straight to d_out high region.
//   phase a/b (x4 ic-chunks): conv1(1->16)+relu+pool2 -> LDS, conv2(16->8) accum.
//   epilogue: relu+pool2 (h2 exchange via LDS), conv3(8->4,1x1) -> d_out low.
// R1: conv1/conv2 use v_pk_fma_f32 (packed fp32, 2 FMA/instr) over oc pairs.
// R2: half tiles -> grid 3072 (12 blocks/CU), LDS 21.3KB (7 blocks/CU resident,
//   28 waves). Kills the 25% dispatch-tail (was 6 blocks/CU at 4 resident) and
//   doubles latency-hiding waves. conv2 splits 8 oc over 2 thread groups
//   (wave-uniform ocg -> weights stay SGPR); h2 re-gathered via LDS (stride 9
//   floats = bank-conflict-free) for conv3. Numerics bit-identical.

typedef float v2f __attribute__((ext_vector_type(2)));

// acc(pair over oc) += w(pair over oc, SGPR) * broadcast(data.word0)
#define PK_FMA_W0(acc, w, d) \
    asm("v_pk_fma_f32 %0, %1, %2, %0 op_sel:[0,0,0] op_sel_hi:[1,0,1]" \
        : "+v"(acc) : "s"(w), "v"(d))
// acc += w * broadcast(data.word1)
#define PK_FMA_W1(acc, w, d) \
    asm("v_pk_fma_f32 %0, %1, %2, %0 op_sel:[0,1,0] op_sel_hi:[1,1,1]" \
        : "+v"(acc) : "s"(w), "v"(d))
// dst = w * broadcast(data.word0)   (accumulator init without v_mov zeroing)
#define PK_MUL_W0(dst, w, d) \
    asm("v_pk_mul_f32 %0, %1, %2 op_sel:[0,0] op_sel_hi:[1,0]" \
        : "=v"(dst) : "s"(w), "v"(d))
#define PK_MUL_W1(dst, w, d) \
    asm("v_pk_mul_f32 %0, %1, %2 op_sel:[0,1] op_sel_hi:[1,1]" \
        : "=v"(dst) : "s"(w), "v"(d))

__global__ __launch_bounds__(256, 6) void fused_all_kernel(
    const float* __restrict__ x,
    const float* __restrict__ w1, const float* __restrict__ b1,
    const float* __restrict__ w2, const float* __restrict__ b2,
    const float* __restrict__ w3, const float* __restrict__ b3,
    float* __restrict__ outLow, float* __restrict__ outHigh)
{
    __shared__ __align__(16) float ca[38 * 72];      // cA tile, rows stride 72
    __shared__ __align__(16) float h1s[4 * 18 * 36]; // conv1 output chunk (reused for h2 xchg)

    int img = blockIdx.x >> 5;
    int t   = blockIdx.x & 31;
    int tyy = t >> 2, txx = t & 3;             // 8x4 tiles: 8 pooled rows x 16 cols
    int hy0 = tyy * 16 - 1, hx0 = txx * 32 - 1; // h1 tile origin (18x34 incl halo)
    int cy0 = tyy * 32 - 3, cx0 = txx * 64 - 3; // cA tile origin (38x70)

    const float* xi = x + img * 262144;        // 512*512 image
    float* hb = outHigh + img * 131072;

    // ---- Phase 0a: interior 32x64 cA (coalesced), cH/cV -> global ----
    #pragma unroll
    for (int k = 0; k < 2; ++k) {
        int i = threadIdx.x + k * 256;
        int row = i >> 4, cg = i & 15;
        int gy = tyy * 32 + row;               // cA row (always in-bounds)
        int gx = txx * 64 + cg * 4;            // cA col, float4-aligned
        const float* r0 = xi + (2 * gy) * 512 + 2 * gx;
        const float* r1 = r0 + 512;
        float4 t0 = *(const float4*)(r0);
        float4 t1 = *(const float4*)(r0 + 4);
        float4 u0 = *(const float4*)(r1);
        float4 u1 = *(const float4*)(r1 + 4);
        float4 vA, vH, vV;
        vA.x = (t0.x + t0.y + u0.x + u0.y) * 0.5f;
        vH.x = (t0.x + t0.y - u0.x - u0.y) * 0.5f;
        vV.x = (t0.x - t0.y + u0.x - u0.y) * 0.5f;
        vA.y = (t0.z + t0.w + u0.z + u0.w) * 0.5f;
        vH.y = (t0.z + t0.w - u0.z - u0.w) * 0.5f;
        vV.y = (t0.z - t0.w + u0.z - u0.w) * 0.5f;
        vA.z = (t1.x + t1.y + u1.x + u1.y) * 0.5f;
        vH.z = (t1.x + t1.y - u1.x - u1.y) * 0.5f;
        vV.z = (t1.x - t1.y + u1.x - u1.y) * 0.5f;
        vA.w = (t1.z + t1.w + u1.z + u1.w) * 0.5f;
        vH.w = (t1.z + t1.w - u1.z - u1.w) * 0.5f;
        vV.w = (t1.z - t1.w + u1.z - u1.w) * 0.5f;
        int po = (gy << 8) + gx;
        *(float4*)(hb + po) = vH;
        *(float4*)(hb + 65536 + po) = vV;
        float* cp = ca + (row + 3) * 72 + cg * 4 + 3;   // odd offset: scalar stores
        cp[0] = vA.x; cp[1] = vA.y; cp[2] = vA.z; cp[3] = vA.w;
    }

    // ---- Phase 0b: 3-wide halo ring of cA (612 points), vA only ----
    // Ring = rows {0,1,2} + rows {35,36,37} (full width 70) + middle rows 3..34
    // with cols {0,1,2} and {67,68,69}.
    for (int i = threadIdx.x; i < 612; i += 256) {
        int r, c;
        if (i < 210)      { r = i / 70;              c = i - r * 70; }
        else if (i < 420) { int j = i - 210; r = 35 + j / 70; c = j - (j / 70) * 70; }
        else              { int j = i - 420; r = 3 + j / 6; int k6 = j - (j / 6) * 6;
                            c = (k6 < 3) ? k6 : (64 + k6); }   // {0,1,2,67,68,69}
        int gy = cy0 + r, gx = cx0 + c;
        float v = 0.f;
        if ((unsigned)gy < 256u && (unsigned)gx < 256u) {
            const float* p0 = xi + (2 * gy) * 512 + 2 * gx;
            float2 a = *(const float2*)(p0);
            float2 b = *(const float2*)(p0 + 512);
            v = (a.x + a.y + b.x + b.y) * 0.5f;
        }
        ca[r * 72 + c] = v;
    }

    // conv2 thread mapping: pos = tid&127 over 8x16 pooled positions,
    // ocg = tid>>7 picks oc {4*ocg .. 4*ocg+3}. Wave-uniform.
    int pos = threadIdx.x & 127;
    int ocg = __builtin_amdgcn_readfirstlane(threadIdx.x >> 7);
    int ly = pos >> 4, lx = pos & 15;

    // conv2 accumulators: 2 oc-pairs for this group x 2x2 window
    v2f acc2[2][2][2];
    #pragma unroll
    for (int o2 = 0; o2 < 2; ++o2)
        #pragma unroll
        for (int r = 0; r < 2; ++r)
            #pragma unroll
            for (int c = 0; c < 2; ++c) acc2[o2][r][c] = (v2f){0.f, 0.f};

    __syncthreads();

    #pragma unroll 1
    for (int cc = 0; cc < 4; ++cc) {
        // conv1 weight pairs over oc for this 4-oc chunk (uniform -> SGPR pairs)
        v2f wp1[2][9];
        #pragma unroll
        for (int o2 = 0; o2 < 2; ++o2)
            #pragma unroll
            for (int k = 0; k < 9; ++k)
                wp1[o2][k] = (v2f){ w1[(cc * 4 + o2 * 2    ) * 9 + k],
                                    w1[(cc * 4 + o2 * 2 + 1) * 9 + k] };
        if (cc) __syncthreads();   // prev chunk's conv2 reads before overwrite

        // Phase a: h1 chunk = pool2(relu(conv1)), 4 oc, 18x34 (incl conv2 halo)
        #pragma unroll 1
        for (int k5 = 0; k5 < 3; ++k5) {
            int i = threadIdx.x + k5 * 256;
            if (i < 612) {
                int hy = i / 34, hx = i - hy * 34;
                const float* pb = ca + (2 * hy) * 72 + 2 * hx;
                v2f pr[4][2];
                #pragma unroll
                for (int r = 0; r < 4; ++r) {
                    pr[r][0] = *(const v2f*)(pb + r * 72);
                    pr[r][1] = *(const v2f*)(pb + r * 72 + 2);
                }
                bool oob = ((unsigned)(hy0 + hy) >= 128u) | ((unsigned)(hx0 + hx) >= 128u);
                v2f am[2][4];   // [ocpair][pos: p00 p01 p10 p11]
                #pragma unroll
                for (int ky = 0; ky < 3; ++ky)
                #pragma unroll
                for (int kx = 0; kx < 3; ++kx) {
                    #pragma unroll
                    for (int o2 = 0; o2 < 2; ++o2)
                    #pragma unroll
                    for (int dy = 0; dy < 2; ++dy)
                    #pragma unroll
                    for (int dx = 0; dx < 2; ++dx) {
                        v2f d = pr[ky + dy][(kx + dx) >> 1];
                        if (ky == 0 && kx == 0) {
                            if (((kx + dx) & 1) == 0) PK_MUL_W0(am[o2][dy * 2 + dx], wp1[o2][0], d);
                            else                      PK_MUL_W1(am[o2][dy * 2 + dx], wp1[o2][0], d);
                        } else {
                            if (((kx + dx) & 1) == 0) PK_FMA_W0(am[o2][dy * 2 + dx], wp1[o2][ky * 3 + kx], d);
                            else                      PK_FMA_W1(am[o2][dy * 2 + dx], wp1[o2][ky * 3 + kx], d);
                        }
                    }
                }
                #pragma unroll
                for (int o2 = 0; o2 < 2; ++o2) {
                    float mx = fmaxf(fmaxf(am[o2][0].x, am[o2][1].x),
                                     fmaxf(am[o2][2].x, am[o2][3].x));
                    float my = fmaxf(fmaxf(am[o2][0].y, am[o2][1].y),
                                     fmaxf(am[o2][2].y, am[o2][3].y));
                    mx = fmaxf(mx + b1[cc * 4 + o2 * 2    ], 0.f);
                    my = fmaxf(my + b1[cc * 4 + o2 * 2 + 1], 0.f);
                    h1s[((o2 * 2    ) * 18 + hy) * 36 + hx] = oob ? 0.f : mx;
                    h1s[((o2 * 2 + 1) * 18 + hy) * 36 + hx] = oob ? 0.f : my;
                }
            }
        }
        __syncthreads();

        // Phase b: conv2 accumulate over these 4 input channels (4 oc per group)
        #pragma unroll
        for (int icl = 0; icl < 4; ++icl) {
            const float* base = h1s + (icl * 18 + ly * 2) * 36 + lx * 2;
            v2f wr[4][2];
            #pragma unroll
            for (int r = 0; r < 4; ++r) {
                wr[r][0] = *(const v2f*)(base + r * 36);
                wr[r][1] = *(const v2f*)(base + r * 36 + 2);
            }
            int ic = cc * 4 + icl;
            #pragma unroll
            for (int ky = 0; ky < 3; ++ky)
            #pragma unroll
            for (int kx = 0; kx < 3; ++kx)
            #pragma unroll
            for (int o2 = 0; o2 < 2; ++o2) {
                int oc0 = ocg * 4 + o2 * 2;
                v2f wv = (v2f){ w2[((oc0    ) * 16 + ic) * 9 + ky * 3 + kx],
                                w2[((oc0 + 1) * 16 + ic) * 9 + ky * 3 + kx] };
                #pragma unroll
                for (int r = 0; r < 2; ++r)
                #pragma unroll
                for (int c = 0; c < 2; ++c) {
                    v2f d = wr[r + ky][(c + kx) >> 1];
                    if (((c + kx) & 1) == 0) PK_FMA_W0(acc2[o2][r][c], wv, d);
                    else                     PK_FMA_W1(acc2[o2][r][c], wv, d);
                }
            }
        }
    }

    // Epilogue: bias+relu+pool2 of conv2 (4 oc per thread), exchange via LDS,
    // then conv3 (1x1, 8->4) -> low
    float h2v[4];
    #pragma unroll
    for (int o2 = 0; o2 < 2; ++o2) {
        float mx = fmaxf(fmaxf(acc2[o2][0][0].x, acc2[o2][0][1].x),
                         fmaxf(acc2[o2][1][0].x, acc2[o2][1][1].x));
        float my = fmaxf(fmaxf(acc2[o2][0][0].y, acc2[o2][0][1].y),
                         fmaxf(acc2[o2][1][0].y, acc2[o2][1][1].y));
        h2v[o2 * 2    ] = fmaxf(mx + b2[ocg * 4 + o2 * 2    ], 0.f);
        h2v[o2 * 2 + 1] = fmaxf(my + b2[ocg * 4 + o2 * 2 + 1], 0.f);
    }
    __syncthreads();                 // conv2 done reading h1s; reuse for h2
    float* hx2 = h1s;                // [128][9] stride 9 -> conflict-free
    #pragma unroll
    for (int j = 0; j < 4; ++j) hx2[pos * 9 + ocg * 4 + j] = h2v[j];
    __syncthreads();

    float hv[8];
    #pragma unroll
    for (int ic = 0; ic < 8; ++ic) hv[ic] = hx2[pos * 9 + ic];
    float* dst = outLow + img * 16384;
    int posg = (tyy * 8 + ly) * 64 + txx * 16 + lx;
    int o3g = ocg;                   // this thread writes oc3 {2*o3g, 2*o3g+1}
    #pragma unroll
    for (int jo = 0; jo < 2; ++jo) {
        int oc3 = o3g * 2 + jo;
        float s = b3[oc3];
        #pragma unroll
        for (int ic = 0; ic < 8; ++ic) s += w3[oc3 * 8 + ic] * hv[ic];
        dst[oc3 * 4096 + posg] = s;
    }
}

extern "C" void kernel_launch(void* const* d_in, const int* in_sizes, int n_in,
                              void* d_out, int out_size, void* d_ws, size_t ws_size,
                              hipStream_t stream) {
    const float* x  = (const float*)d_in[0];
    const float* w1 = (const float*)d_in[1];
    const float* b1 = (const float*)d_in[2];
    const float* w2 = (const float*)d_in[3];
    const float* b2 = (const float*)d_in[4];
    const float* w3 = (const float*)d_in[5];
    const float* b3 = (const float*)d_in[6];
    float* out     = (float*)d_out;
    float* outLow  = out;                 // 1,572,864 floats
    float* outHigh = out + 1572864;       // 12,582,912 floats

    fused_all_kernel<<<3072, 256, 0, stream>>>(x, w1, b1, w2, b2, w3, b3,
                                               outLow, outHigh);
}

// Round 4
// 208.663 us; speedup vs baseline: 1.1514x; 1.0051x over previous
//
#include <hip/hip_runtime.h>

// Problem: B=32, C=3, H=512, W=512 -> NIMG = 96 flat images
// ONE kernel: per block (img, 8x16-pooled half-tile):
//   phase 0: Haar DWT of x -> cA 38x70 tile in LDS (zero-pad OOB); interior
//            32x64 cH/cV written straight to d_out high region.
//   phase a/b (x4 ic-chunks): conv1(1->16)+relu+pool2 -> LDS, conv2(16->8) accum.
//   epilogue: relu+pool2 (h2 exchange via LDS), conv3(8->4,1x1) -> d_out low.
// R1: conv1/conv2 use v_pk_fma_f32 (packed fp32) over oc pairs.
// R2: half tiles -> grid 3072 (12 blocks/CU), split conv2 oc over 2 groups.
// R3: LDS 20,480 B (ca stride 70, h1s stride 34) -> 8 blocks/CU = 32 waves
//   (occupancy cap); conv1/halo task loops re-indexed 153-per-wave so all 4
//   SIMDs carry equal VALU load (was: wave0/1 50% heavier); conv2 weight pairs
//   hoisted per-icl ahead of LDS reads. Numerics bit-identical.
// R4: resubmit of R3 (round-3 bench was an infra failure: container acquisition
//   died before compile/run; no counters returned; source audit found no fault).

typedef float v2f __attribute__((ext_vector_type(2)));

// acc(pair over oc) += w(pair over oc, SGPR) * broadcast(data.word0)
#define PK_FMA_W0(acc, w, d) \
    asm("v_pk_fma_f32 %0, %1, %2, %0 op_sel:[0,0,0] op_sel_hi:[1,0,1]" \
        : "+v"(acc) : "s"(w), "v"(d))
// acc += w * broadcast(data.word1)
#define PK_FMA_W1(acc, w, d) \
    asm("v_pk_fma_f32 %0, %1, %2, %0 op_sel:[0,1,0] op_sel_hi:[1,1,1]" \
        : "+v"(acc) : "s"(w), "v"(d))
// dst = w * broadcast(data.word0)   (accumulator init without v_mov zeroing)
#define PK_MUL_W0(dst, w, d) \
    asm("v_pk_mul_f32 %0, %1, %2 op_sel:[0,0] op_sel_hi:[1,0]" \
        : "=v"(dst) : "s"(w), "v"(d))
#define PK_MUL_W1(dst, w, d) \
    asm("v_pk_mul_f32 %0, %1, %2 op_sel:[0,1] op_sel_hi:[1,1]" \
        : "=v"(dst) : "s"(w), "v"(d))

__global__ __launch_bounds__(256, 8) void fused_all_kernel(
    const float* __restrict__ x,
    const float* __restrict__ w1, const float* __restrict__ b1,
    const float* __restrict__ w2, const float* __restrict__ b2,
    const float* __restrict__ w3, const float* __restrict__ b3,
    float* __restrict__ outLow, float* __restrict__ outHigh)
{
    __shared__ __align__(16) float ca[38 * 70];      // cA tile, rows stride 70
    __shared__ __align__(16) float h1s[4 * 18 * 34]; // conv1 output chunk (reused for h2 xchg)

    int img = blockIdx.x >> 5;
    int t   = blockIdx.x & 31;
    int tyy = t >> 2, txx = t & 3;             // 8x4 tiles: 8 pooled rows x 16 cols
    int hy0 = tyy * 16 - 1, hx0 = txx * 32 - 1; // h1 tile origin (18x34 incl halo)
    int cy0 = tyy * 32 - 3, cx0 = txx * 64 - 3; // cA tile origin (38x70)

    const float* xi = x + img * 262144;        // 512*512 image
    float* hb = outHigh + img * 131072;

    int wvi = threadIdx.x >> 6;                // wave index 0..3
    int lni = threadIdx.x & 63;                // lane

    // ---- Phase 0a: interior 32x64 cA (coalesced), cH/cV -> global ----
    #pragma unroll
    for (int k = 0; k < 2; ++k) {
        int i = threadIdx.x + k * 256;
        int row = i >> 4, cg = i & 15;
        int gy = tyy * 32 + row;               // cA row (always in-bounds)
        int gx = txx * 64 + cg * 4;            // cA col, float4-aligned
        const float* r0 = xi + (2 * gy) * 512 + 2 * gx;
        const float* r1 = r0 + 512;
        float4 t0 = *(const float4*)(r0);
        float4 t1 = *(const float4*)(r0 + 4);
        float4 u0 = *(const float4*)(r1);
        float4 u1 = *(const float4*)(r1 + 4);
        float4 vA, vH, vV;
        vA.x = (t0.x + t0.y + u0.x + u0.y) * 0.5f;
        vH.x = (t0.x + t0.y - u0.x - u0.y) * 0.5f;
        vV.x = (t0.x - t0.y + u0.x - u0.y) * 0.5f;
        vA.y = (t0.z + t0.w + u0.z + u0.w) * 0.5f;
        vH.y = (t0.z + t0.w - u0.z - u0.w) * 0.5f;
        vV.y = (t0.z - t0.w + u0.z - u0.w) * 0.5f;
        vA.z = (t1.x + t1.y + u1.x + u1.y) * 0.5f;
        vH.z = (t1.x + t1.y - u1.x - u1.y) * 0.5f;
        vV.z = (t1.x - t1.y + u1.x - u1.y) * 0.5f;
        vA.w = (t1.z + t1.w + u1.z + u1.w) * 0.5f;
        vH.w = (t1.z + t1.w - u1.z - u1.w) * 0.5f;
        vV.w = (t1.z - t1.w + u1.z - u1.w) * 0.5f;
        int po = (gy << 8) + gx;
        *(float4*)(hb + po) = vH;
        *(float4*)(hb + 65536 + po) = vV;
        float* cp = ca + (row + 3) * 70 + cg * 4 + 3;   // odd offset: scalar stores
        cp[0] = vA.x; cp[1] = vA.y; cp[2] = vA.z; cp[3] = vA.w;
    }

    // ---- Phase 0b: 3-wide halo ring of cA (612 points), vA only ----
    // Ring = rows {0,1,2} + rows {35,36,37} (full width 70) + middle rows 3..34
    // with cols {0,1,2} and {67,68,69}.  153 tasks per wave (SIMD-balanced).
    #pragma unroll
    for (int j = 0; j < 3; ++j) {
        if (j < 2 || lni < 25) {
            int i = wvi * 153 + j * 64 + lni;
            int r, c;
            if (i < 210)      { r = i / 70;              c = i - r * 70; }
            else if (i < 420) { int jj = i - 210; r = 35 + jj / 70; c = jj - (jj / 70) * 70; }
            else              { int jj = i - 420; r = 3 + jj / 6; int k6 = jj - (jj / 6) * 6;
                                c = (k6 < 3) ? k6 : (64 + k6); }   // {0,1,2,67,68,69}
            int gy = cy0 + r, gx = cx0 + c;
            float v = 0.f;
            if ((unsigned)gy < 256u && (unsigned)gx < 256u) {
                const float* p0 = xi + (2 * gy) * 512 + 2 * gx;
                float2 a = *(const float2*)(p0);
                float2 b = *(const float2*)(p0 + 512);
                v = (a.x + a.y + b.x + b.y) * 0.5f;
            }
            ca[r * 70 + c] = v;
        }
    }

    // conv2 thread mapping: pos = tid&127 over 8x16 pooled positions,
    // ocg = tid>>7 picks oc {4*ocg .. 4*ocg+3}. Wave-uniform.
    int pos = threadIdx.x & 127;
    int ocg = __builtin_amdgcn_readfirstlane(threadIdx.x >> 7);
    int ly = pos >> 4, lx = pos & 15;

    // conv2 accumulators: 2 oc-pairs for this group x 2x2 window
    v2f acc2[2][2][2];
    #pragma unroll
    for (int o2 = 0; o2 < 2; ++o2)
        #pragma unroll
        for (int r = 0; r < 2; ++r)
            #pragma unroll
            for (int c = 0; c < 2; ++c) acc2[o2][r][c] = (v2f){0.f, 0.f};

    __syncthreads();

    #pragma unroll 1
    for (int cc = 0; cc < 4; ++cc) {
        // conv1 weight pairs over oc for this 4-oc chunk (uniform -> SGPR pairs)
        v2f wp1[2][9];
        #pragma unroll
        for (int o2 = 0; o2 < 2; ++o2)
            #pragma unroll
            for (int k = 0; k < 9; ++k)
                wp1[o2][k] = (v2f){ w1[(cc * 4 + o2 * 2    ) * 9 + k],
                                    w1[(cc * 4 + o2 * 2 + 1) * 9 + k] };
        if (cc) __syncthreads();   // prev chunk's conv2 reads before overwrite

        // Phase a: h1 chunk = pool2(relu(conv1)), 4 oc, 18x34 (incl conv2 halo)
        // 612 tasks, 153 per wave (SIMD-balanced: 2 full passes + 25 lanes)
        #pragma unroll 1
        for (int j = 0; j < 3; ++j) {
            if (j < 2 || lni < 25) {
                int i = wvi * 153 + j * 64 + lni;
                int hy = i / 34, hx = i - hy * 34;
                const float* pb = ca + (2 * hy) * 70 + 2 * hx;
                v2f pr[4][2];
                #pragma unroll
                for (int r = 0; r < 4; ++r) {
                    pr[r][0] = *(const v2f*)(pb + r * 70);
                    pr[r][1] = *(const v2f*)(pb + r * 70 + 2);
                }
                bool oob = ((unsigned)(hy0 + hy) >= 128u) | ((unsigned)(hx0 + hx) >= 128u);
                v2f am[2][4];   // [ocpair][pos: p00 p01 p10 p11]
                #pragma unroll
                for (int ky = 0; ky < 3; ++ky)
                #pragma unroll
                for (int kx = 0; kx < 3; ++kx) {
                    #pragma unroll
                    for (int o2 = 0; o2 < 2; ++o2)
                    #pragma unroll
                    for (int dy = 0; dy < 2; ++dy)
                    #pragma unroll
                    for (int dx = 0; dx < 2; ++dx) {
                        v2f d = pr[ky + dy][(kx + dx) >> 1];
                        if (ky == 0 && kx == 0) {
                            if (((kx + dx) & 1) == 0) PK_MUL_W0(am[o2][dy * 2 + dx], wp1[o2][0], d);
                            else                      PK_MUL_W1(am[o2][dy * 2 + dx], wp1[o2][0], d);
                        } else {
                            if (((kx + dx) & 1) == 0) PK_FMA_W0(am[o2][dy * 2 + dx], wp1[o2][ky * 3 + kx], d);
                            else                      PK_FMA_W1(am[o2][dy * 2 + dx], wp1[o2][ky * 3 + kx], d);
                        }
                    }
                }
                #pragma unroll
                for (int o2 = 0; o2 < 2; ++o2) {
                    float mx = fmaxf(fmaxf(am[o2][0].x, am[o2][1].x),
                                     fmaxf(am[o2][2].x, am[o2][3].x));
                    float my = fmaxf(fmaxf(am[o2][0].y, am[o2][1].y),
                                     fmaxf(am[o2][2].y, am[o2][3].y));
                    mx = fmaxf(mx + b1[cc * 4 + o2 * 2    ], 0.f);
                    my = fmaxf(my + b1[cc * 4 + o2 * 2 + 1], 0.f);
                    h1s[((o2 * 2    ) * 18 + hy) * 34 + hx] = oob ? 0.f : mx;
                    h1s[((o2 * 2 + 1) * 18 + hy) * 34 + hx] = oob ? 0.f : my;
                }
            }
        }
        __syncthreads();

        // Phase b: conv2 accumulate over these 4 input channels (4 oc per group)
        #pragma unroll
        for (int icl = 0; icl < 4; ++icl) {
            int ic = cc * 4 + icl;
            // weight pairs hoisted ahead of LDS reads (s_load overlaps ds_read)
            v2f wl[2][9];
            #pragma unroll
            for (int o2 = 0; o2 < 2; ++o2) {
                int oc0 = ocg * 4 + o2 * 2;
                #pragma unroll
                for (int k = 0; k < 9; ++k)
                    wl[o2][k] = (v2f){ w2[((oc0    ) * 16 + ic) * 9 + k],
                                       w2[((oc0 + 1) * 16 + ic) * 9 + k] };
            }
            const float* base = h1s + (icl * 18 + ly * 2) * 34 + lx * 2;
            v2f wr[4][2];
            #pragma unroll
            for (int r = 0; r < 4; ++r) {
                wr[r][0] = *(const v2f*)(base + r * 34);
                wr[r][1] = *(const v2f*)(base + r * 34 + 2);
            }
            #pragma unroll
            for (int ky = 0; ky < 3; ++ky)
            #pragma unroll
            for (int kx = 0; kx < 3; ++kx)
            #pragma unroll
            for (int o2 = 0; o2 < 2; ++o2) {
                #pragma unroll
                for (int r = 0; r < 2; ++r)
                #pragma unroll
                for (int c = 0; c < 2; ++c) {
                    v2f d = wr[r + ky][(c + kx) >> 1];
                    if (((c + kx) & 1) == 0) PK_FMA_W0(acc2[o2][r][c], wl[o2][ky * 3 + kx], d);
                    else                     PK_FMA_W1(acc2[o2][r][c], wl[o2][ky * 3 + kx], d);
                }
            }
        }
    }

    // Epilogue: bias+relu+pool2 of conv2 (4 oc per thread), exchange via LDS,
    // then conv3 (1x1, 8->4) -> low
    float h2v[4];
    #pragma unroll
    for (int o2 = 0; o2 < 2; ++o2) {
        float mx = fmaxf(fmaxf(acc2[o2][0][0].x, acc2[o2][0][1].x),
                         fmaxf(acc2[o2][1][0].x, acc2[o2][1][1].x));
        float my = fmaxf(fmaxf(acc2[o2][0][0].y, acc2[o2][0][1].y),
                         fmaxf(acc2[o2][1][0].y, acc2[o2][1][1].y));
        h2v[o2 * 2    ] = fmaxf(mx + b2[ocg * 4 + o2 * 2    ], 0.f);
        h2v[o2 * 2 + 1] = fmaxf(my + b2[ocg * 4 + o2 * 2 + 1], 0.f);
    }
    __syncthreads();                 // conv2 done reading h1s; reuse for h2
    float* hx2 = h1s;                // [128][9] stride 9 -> conflict-free
    #pragma unroll
    for (int j = 0; j < 4; ++j) hx2[pos * 9 + ocg * 4 + j] = h2v[j];
    __syncthreads();

    float hv[8];
    #pragma unroll
    for (int ic = 0; ic < 8; ++ic) hv[ic] = hx2[pos * 9 + ic];
    float* dst = outLow + img * 16384;
    int posg = (tyy * 8 + ly) * 64 + txx * 16 + lx;
    int o3g = ocg;                   // this thread writes oc3 {2*o3g, 2*o3g+1}
    #pragma unroll
    for (int jo = 0; jo < 2; ++jo) {
        int oc3 = o3g * 2 + jo;
        float s = b3[oc3];
        #pragma unroll
        for (int ic = 0; ic < 8; ++ic) s += w3[oc3 * 8 + ic] * hv[ic];
        dst[oc3 * 4096 + posg] = s;
    }
}

extern "C" void kernel_launch(void* const* d_in, const int* in_sizes, int n_in,
                              void* d_out, int out_size, void* d_ws, size_t ws_size,
                              hipStream_t stream) {
    const float* x  = (const float*)d_in[0];
    const float* w1 = (const float*)d_in[1];
    const float* b1 = (const float*)d_in[2];
    const float* w2 = (const float*)d_in[3];
    const float* b2 = (const float*)d_in[4];
    const float* w3 = (const float*)d_in[5];
    const float* b3 = (const float*)d_in[6];
    float* out     = (float*)d_out;
    float* outLow  = out;                 // 1,572,864 floats
    float* outHigh = out + 1572864;       // 12,582,912 floats

    fused_all_kernel<<<3072, 256, 0, stream>>>(x, w1, b1, w2, b2, w3, b3,
                                               outLow, outHigh);
}